// Round 2
// baseline (922.684 us; speedup 1.0000x reference)
//
#include <hip/hip_runtime.h>
#include <math.h>

// MemoryBank: B=64, C=1501, D=2048, fp32
//   out0 selected     [B,D]    = memory[cls_list]            (original memory)
//   out1 tmp_repeated [B,C,D]  = B copies of tmp_memory      (memory w/ rows cls_list <- x)
//   out2 new_mem      [C,D]    = l2normalize(memory*(1-a) + tmp_memory*a)
//
// R2 = MEASUREMENT ROUND. R0 (NT slab-stride) and R1 (fill-shaped plain) and the
// prior session's best are all ~780 us => dur_us has a large fixed component
// (the 510 us / 3.2 GB re-poison fill visible in counters, likely inside the
// timed graph). To split fixed-vs-kernel time, launch mb_replicate TWICE
// (idempotent). Marginal cost = t_replicate exactly:
//   T1 (replicate ~3 TB/s, improvable): dur ~1040 us
//   T2 (replicate at 6.27 TB/s write ceiling, rooflined): dur ~910 us

#define ALPHA 0.01f
#define EPS_  1e-7f
#define B_    64
#define C_    1501
#define D_    2048
#define T_    256          // threads per block; D_/4 = 512 float4 = 2 per thread
#define REP_PER_BLK 7      // 63 replicated slabs = 7 * 9
#define REP_GRID_Y  9

typedef float f32x4 __attribute__((ext_vector_type(4)));

// ---------------------------------------------------------------------------
// Kernel A: per class row c — mask/winner, selected rows, new_mem, tmp row
// into out1 slab b=0.
// ---------------------------------------------------------------------------
__global__ __launch_bounds__(T_) void mb_prep(
    const float* __restrict__ x,    // [B,D]
    const int*   __restrict__ cls,  // [B]
    const float* __restrict__ mem,  // [C,D]
    float*       __restrict__ out)  // [B*D + B*C*D + C*D]
{
    const int c   = blockIdx.x;
    const int tid = threadIdx.x;

    __shared__ unsigned long long s_mask;
    if (tid < 64) {
        int cb = cls[tid];
        unsigned long long m = __ballot(cb == c);
        if (tid == 0) s_mask = m;
    }
    __syncthreads();
    const unsigned long long mask = s_mask;
    const int winner = mask ? (63 - __clzll(mask)) : -1;

    const f32x4* mrow = (const f32x4*)(mem + (size_t)c * D_);
    f32x4 m0 = mrow[tid];
    f32x4 m1 = mrow[tid + T_];

    f32x4 t0 = m0, t1 = m1;
    if (winner >= 0) {
        const f32x4* xrow = (const f32x4*)(x + (size_t)winner * D_);
        t0 = xrow[tid];
        t1 = xrow[tid + T_];
    }

    f32x4 n0 = m0 * (1.0f - ALPHA) + t0 * ALPHA;
    f32x4 n1 = m1 * (1.0f - ALPHA) + t1 * ALPHA;

    float ss = n0.x*n0.x + n0.y*n0.y + n0.z*n0.z + n0.w*n0.w
             + n1.x*n1.x + n1.y*n1.y + n1.z*n1.z + n1.w*n1.w;
    #pragma unroll
    for (int off = 32; off > 0; off >>= 1)
        ss += __shfl_xor(ss, off, 64);
    __shared__ float s_part[T_ / 64];
    if ((tid & 63) == 0) s_part[tid >> 6] = ss;
    __syncthreads();
    const float total = s_part[0] + s_part[1] + s_part[2] + s_part[3];
    const float inv = 1.0f / (sqrtf(total) + EPS_);

    f32x4* out_sel = (f32x4*)out;                                            // [B][D]
    f32x4* out_rep = (f32x4*)(out + (size_t)B_ * D_);                        // [B][C][D]
    f32x4* out_new = (f32x4*)(out + (size_t)B_ * D_ + (size_t)B_ * C_ * D_); // [C][D]

    const size_t rbase = (size_t)c * (D_ / 4);

    out_rep[rbase + tid]      = t0;
    out_rep[rbase + tid + T_] = t1;

    out_new[rbase + tid]      = n0 * inv;
    out_new[rbase + tid + T_] = n1 * inv;

    unsigned long long mm = mask;
    while (mm) {
        const int b = __ffsll(mm) - 1;
        mm &= mm - 1;
        const size_t base = (size_t)b * (D_ / 4);
        out_sel[base + tid]      = m0;
        out_sel[base + tid + T_] = m1;
    }
}

// ---------------------------------------------------------------------------
// Kernel B: replicate out1 slab 0 -> slabs 1..63.
// ---------------------------------------------------------------------------
__global__ __launch_bounds__(T_) void mb_replicate(float* __restrict__ out)
{
    const int c   = blockIdx.x;
    const int by  = blockIdx.y;
    const int tid = threadIdx.x;

    f32x4* rep = (f32x4*)(out + (size_t)B_ * D_);
    const size_t slab  = (size_t)C_ * (D_ / 4);
    const size_t rbase = (size_t)c * (D_ / 4);

    f32x4 v0 = rep[rbase + tid];
    f32x4 v1 = rep[rbase + tid + T_];

    const int b0 = 1 + by * REP_PER_BLK;
    #pragma unroll
    for (int k = 0; k < REP_PER_BLK; ++k) {
        const size_t dst = (size_t)(b0 + k) * slab + rbase;
        rep[dst + tid]      = v0;
        rep[dst + tid + T_] = v1;
    }
}

extern "C" void kernel_launch(void* const* d_in, const int* in_sizes, int n_in,
                              void* d_out, int out_size, void* d_ws, size_t ws_size,
                              hipStream_t stream) {
    const float* x   = (const float*)d_in[0];
    const int*   cls = (const int*)  d_in[1];
    const float* mem = (const float*)d_in[2];
    float*       out = (float*)d_out;

    mb_prep<<<C_, T_, 0, stream>>>(x, cls, mem, out);
    // Double-launch: marginal dur_us vs R1 == t_replicate (idempotent rewrite).
    mb_replicate<<<dim3(C_, REP_GRID_Y), T_, 0, stream>>>(out);
    mb_replicate<<<dim3(C_, REP_GRID_Y), T_, 0, stream>>>(out);
}

// Round 5
// 779.698 us; speedup vs baseline: 1.1834x; 1.1834x over previous
//
#include <hip/hip_runtime.h>
#include <math.h>

// MemoryBank: B=64, C=1501, D=2048, fp32
//   out0 selected     [B,D]    = memory[cls_list]            (original memory)
//   out1 tmp_repeated [B,C,D]  = B copies of tmp_memory      (memory w/ rows cls_list <- x)
//   out2 new_mem      [C,D]    = l2normalize(memory*(1-a) + tmp_memory*a)
//
// R5 = R3/R4 resubmitted verbatim (R3: container failed; R4: GPU acquisition
// timeout — neither reached the kernel). Single fused kernel. R2's
// double-launch measurement pinned the decomposition: replicate phase =
// 137 us for 775 MB (5.66 TB/s ~= 90% of the same-run rocclr fill ceiling
// 6.27 TB/s); fixed harness overhead (3.2 GB re-poison fill @ ~510 us +
// resets) ~= 640 us. Kernel headroom <= ~15 us. Fusion removes the second
// launch + inter-kernel dependency + slab-0 read-back: every block recomputes
// mask/winner (64 int reads, free) and sources its row directly from mem/x
// (12 MB, MALL-resident after 1st touch).
//
// grid = (C, 8); each block writes its row into 8 of the 64 slabs.
// by==0 block additionally writes selected rows + new_mem row.

#define ALPHA 0.01f
#define EPS_  1e-7f
#define B_    64
#define C_    1501
#define D_    2048
#define T_    256          // threads per block; D_/4 = 512 float4 = 2 per thread
#define SLABS_PER_BLK 8    // 64 slabs = 8 y-blocks * 8
#define GRID_Y        8

typedef float f32x4 __attribute__((ext_vector_type(4)));

__global__ __launch_bounds__(T_) void mb_fused(
    const float* __restrict__ x,    // [B,D]
    const int*   __restrict__ cls,  // [B]
    const float* __restrict__ mem,  // [C,D]
    float*       __restrict__ out)  // [B*D + B*C*D + C*D]
{
    const int c   = blockIdx.x;
    const int by  = blockIdx.y;
    const int tid = threadIdx.x;

    // which b's (if any) map to this row; winner = max b (last write wins)
    __shared__ unsigned long long s_mask;
    if (tid < 64) {
        int cb = cls[tid];
        unsigned long long m = __ballot(cb == c);
        if (tid == 0) s_mask = m;
    }
    __syncthreads();
    const unsigned long long mask = s_mask;
    const int winner = mask ? (63 - __clzll(mask)) : -1;

    // load memory row (2 float4 per thread, coalesced; MALL-hit for by>0)
    const f32x4* mrow = (const f32x4*)(mem + (size_t)c * D_);
    f32x4 m0 = mrow[tid];
    f32x4 m1 = mrow[tid + T_];

    // tmp_memory row: x[winner] if scattered into, else memory row
    f32x4 t0 = m0, t1 = m1;
    if (winner >= 0) {
        const f32x4* xrow = (const f32x4*)(x + (size_t)winner * D_);
        t0 = xrow[tid];
        t1 = xrow[tid + T_];
    }

    // output pointers (flat concatenation in return order)
    f32x4* out_sel = (f32x4*)out;                                            // [B][D]
    f32x4* out_rep = (f32x4*)(out + (size_t)B_ * D_);                        // [B][C][D]
    f32x4* out_new = (f32x4*)(out + (size_t)B_ * D_ + (size_t)B_ * C_ * D_); // [C][D]

    const size_t slab  = (size_t)C_ * (D_ / 4);
    const size_t rbase = (size_t)c * (D_ / 4);

    // this block's 8 slabs of tmp_repeated
    const int b0 = by * SLABS_PER_BLK;
    #pragma unroll
    for (int k = 0; k < SLABS_PER_BLK; ++k) {
        const size_t dst = (size_t)(b0 + k) * slab + rbase;
        out_rep[dst + tid]      = t0;
        out_rep[dst + tid + T_] = t1;
    }

    if (by != 0) return;

    // --- by==0 extras: EMA + L2-normalized new_mem row ---
    f32x4 n0 = m0 * (1.0f - ALPHA) + t0 * ALPHA;
    f32x4 n1 = m1 * (1.0f - ALPHA) + t1 * ALPHA;

    float ss = n0.x*n0.x + n0.y*n0.y + n0.z*n0.z + n0.w*n0.w
             + n1.x*n1.x + n1.y*n1.y + n1.z*n1.z + n1.w*n1.w;
    #pragma unroll
    for (int off = 32; off > 0; off >>= 1)
        ss += __shfl_xor(ss, off, 64);
    __shared__ float s_part[T_ / 64];
    if ((tid & 63) == 0) s_part[tid >> 6] = ss;
    __syncthreads();
    const float total = s_part[0] + s_part[1] + s_part[2] + s_part[3];
    const float inv = 1.0f / (sqrtf(total) + EPS_);

    out_new[rbase + tid]      = n0 * inv;
    out_new[rbase + tid + T_] = n1 * inv;

    // selected rows: every b with cls[b]==c gets the ORIGINAL memory row
    unsigned long long mm = mask;
    while (mm) {
        const int b = __ffsll(mm) - 1;
        mm &= mm - 1;
        const size_t base = (size_t)b * (D_ / 4);
        out_sel[base + tid]      = m0;
        out_sel[base + tid + T_] = m1;
    }
}

extern "C" void kernel_launch(void* const* d_in, const int* in_sizes, int n_in,
                              void* d_out, int out_size, void* d_ws, size_t ws_size,
                              hipStream_t stream) {
    const float* x   = (const float*)d_in[0];
    const int*   cls = (const int*)  d_in[1];
    const float* mem = (const float*)d_in[2];
    float*       out = (float*)d_out;

    mb_fused<<<dim3(C_, GRID_Y), T_, 0, stream>>>(x, cls, mem, out);
}